// Round 11
// baseline (264.110 us; speedup 1.0000x reference)
//
#include <hip/hip_runtime.h>
#include <hip/hip_bf16.h>

// GraphConv: out = sum_a att[a] * (adj_a @ (X@W + b))
// N=8192, A=3, D_IN=256, D_OUT=64. fp32 in/out.
// Stacked-K GEMM  C[8192,64] = [adj0|adj1|adj2] @ [att0*S; att1*S; att2*S],
// S = X@W+b in bf16, packed MFMA-B-fragment order (d_ws).
// R11 = R10 with INTERLEAVED chunk->q mapping (c = q + 4j instead of
// blocked quarters): the 4 q-blocks of a strip (adjacent bids, near-
// lockstep on 4 XCDs) read CONSECUTIVE 2KB spans of each row at the same
// time -> ~8KB gathered per DRAM page visit instead of 2KB. Same bytes,
// same instructions, k-order only. No stagger (lockstep is the point).

#define NNODES 8192
#define DIN    256
#define DOUT   64
#define NA     3
#define KSTACK (NA * NNODES)     // 24576
#define BK     512
#define NCHT   (KSTACK / BK)     // 48 total chunks
#define NITER  (NCHT / 4)        // 12 per q-block
#define NSTRIP (NNODES / 64)     // 128

typedef float f32x4 __attribute__((ext_vector_type(4)));
typedef short s16x8 __attribute__((ext_vector_type(8)));

__device__ __forceinline__ unsigned short f2bf(float f) {
    __hip_bfloat16 h = __float2bfloat16(f);
    return __builtin_bit_cast(unsigned short, h);
}

__device__ __forceinline__ s16x8 pack8(f32x4 a, f32x4 b) {
    s16x8 o;
    o[0] = (short)f2bf(a[0]); o[1] = (short)f2bf(a[1]);
    o[2] = (short)f2bf(a[2]); o[3] = (short)f2bf(a[3]);
    o[4] = (short)f2bf(b[0]); o[5] = (short)f2bf(b[1]);
    o[6] = (short)f2bf(b[2]); o[7] = (short)f2bf(b[3]);
    return o;
}

__device__ __forceinline__ void gload_lds16(const float* g, float* l) {
    // width 16B, offset 0, aux=2 (NT: adj is single-use, keep B in L2)
    __builtin_amdgcn_global_load_lds(
        (const __attribute__((address_space(1))) void*)g,
        (__attribute__((address_space(3))) void*)l, 16, 0, 2);
}

// ---------------------------------------------------------------------------
// Kernel 0: zero d_out (gemm accumulates into it atomically).
// ---------------------------------------------------------------------------
__global__ __launch_bounds__(256) void zero_out(float* __restrict__ out) {
    f32x4 z = {0.f, 0.f, 0.f, 0.f};
    ((f32x4*)out)[(blockIdx.x << 8) + threadIdx.x] = z;
}

// ---------------------------------------------------------------------------
// Kernel 1: S = X@W + b; write att[a]*S in packed bf16 B-fragment layout:
// tile (kt_abs, nt): B[k_local][col], k_local = (lane>>4)*8 + j, col = lane&15;
// flat shorts = (kt_abs*4 + nt)*512 + lane*8 + j.
// ---------------------------------------------------------------------------
__global__ __launch_bounds__(256) void prep_support(
    const float* __restrict__ x, const float* __restrict__ w,
    const float* __restrict__ bias, const float* __restrict__ att,
    unsigned short* __restrict__ Bp)
{
    const int t = threadIdx.x;
    const int d = t & 63;
    const int m = (blockIdx.x << 2) + (t >> 6);

    const float* xr = x + (size_t)m * DIN;
    float acc = bias[d];
#pragma unroll 4
    for (int k = 0; k < DIN; k += 4) {
        f32x4 xv = *(const f32x4*)(xr + k);
        acc += xv[0] * w[(k + 0) * DOUT + d];
        acc += xv[1] * w[(k + 1) * DOUT + d];
        acc += xv[2] * w[(k + 2) * DOUT + d];
        acc += xv[3] * w[(k + 3) * DOUT + d];
    }

    const int kt   = m >> 5;
    const int kl   = m & 31;
    const int lane = ((kl >> 3) << 4) | (d & 15);
    const int j    = kl & 7;
    const int nt   = d >> 4;

    const size_t base    = (size_t)(kt * 4 + nt) * 512 + lane * 8 + j;
    const size_t aStride = (size_t)(NNODES / 32) * 4 * 512;

    const float a0 = att[0], a1 = att[1], a2 = att[2];
    Bp[base]               = f2bf(a0 * acc);
    Bp[base + aStride]     = f2bf(a1 * acc);
    Bp[base + 2 * aStride] = f2bf(a2 * acc);
}

// ---------------------------------------------------------------------------
// Kernel 2: bid = strip*4 + q. Wave wv owns rows [strip*64 + wv*16, +16);
// q-block handles chunks c = q + 4j (j = 0..11), so the strip's 4 blocks
// sweep each row's k-space contiguously in lockstep (8KB/row per step).
// Per chunk: 32x global_load_lds (1 instr = 1KB half-row; 2KB/row total),
// vmcnt(0), then 16 k-tiles of {2 swizzled ds_read_b128, pack, 4 B-frag
// loads (L2), 4 mfma_16x16x32_bf16}. No barriers, wave-private 32KB bufs.
// Atomic fp32 epilogue (4 contributions/element).
// ---------------------------------------------------------------------------
__global__ __launch_bounds__(256, 1) void graphconv_gemm(
    const float* __restrict__ adj, const unsigned short* __restrict__ Bp,
    float* __restrict__ out)
{
    __shared__ float ldsf[32768];            // 128 KB: wave wv -> [wv*8192, +8192)

    const int tid  = threadIdx.x;
    const int wv   = tid >> 6;
    const int lane = tid & 63;
    const int r    = lane & 15;              // A row within tile / C col
    const int g    = lane >> 4;              // k-subgroup
    const int r7   = r & 7;
    const int q     = blockIdx.x & 3;        // chunk-interleave class
    const int strip = blockIdx.x >> 2;
    const int row0  = strip * 64 + wv * 16;

    float* wbuf = &ldsf[wv << 13];           // 32 KB wave-private buffer

    f32x4 acc0 = {0.f, 0.f, 0.f, 0.f};
    f32x4 acc1 = {0.f, 0.f, 0.f, 0.f};
    f32x4 acc2 = {0.f, 0.f, 0.f, 0.f};
    f32x4 acc3 = {0.f, 0.f, 0.f, 0.f};

    for (int j = 0; j < NITER; ++j) {
        const int c  = q + (j << 2);         // interleaved chunk index
        const int k0 = c * BK;               // stacked k
        const float* ab = adj + ((size_t)(k0 >> 13) << 26) + (k0 & 8191);

        // stage 16 rows x 2KB (2 halves of 1KB), linear LDS dest +
        // XOR-preswizzled source (swizzle within each 64-slot half)
#pragma unroll
        for (int p = 0; p < 16; ++p) {
            const float* rpg = ab + (size_t)(row0 + p) * NNODES;
            const int sl = ((lane ^ (p & 7)) << 2);
            float* ld = wbuf + (p << 9) + (lane << 2);
            gload_lds16(rpg + sl,       ld);
            gload_lds16(rpg + 256 + sl, ld + 256);
        }
        asm volatile("s_waitcnt vmcnt(0)" ::: "memory");
        __builtin_amdgcn_sched_barrier(0);

        const s16x8* bp = (const s16x8*)Bp + ((size_t)(k0 >> 5) << 8) + lane;
        const float* lrow = wbuf + (r << 9); // row r base (512 floats/row)
#pragma unroll
        for (int t = 0; t < 16; ++t) {
            // logical 16B slots a0 = t*8+2g, a1 = a0+1 (0..127);
            // physical = (a & 64) | ((a & 63) ^ r7)
            const int a0 = (t << 3) + 2 * g;
            const int a1 = a0 + 1;
            const int p0 = (a0 & 64) | ((a0 & 63) ^ r7);
            const int p1 = (a1 & 64) | ((a1 & 63) ^ r7);
            f32x4 v0 = *(const f32x4*)(lrow + (p0 << 2));
            f32x4 v1 = *(const f32x4*)(lrow + (p1 << 2));
            s16x8 af = pack8(v0, v1);
            s16x8 b0 = bp[0];
            s16x8 b1 = bp[64];
            s16x8 b2 = bp[128];
            s16x8 b3 = bp[192];
            acc0 = __builtin_amdgcn_mfma_f32_16x16x32_bf16(af, b0, acc0, 0, 0, 0);
            acc1 = __builtin_amdgcn_mfma_f32_16x16x32_bf16(af, b1, acc1, 0, 0, 0);
            acc2 = __builtin_amdgcn_mfma_f32_16x16x32_bf16(af, b2, acc2, 0, 0, 0);
            acc3 = __builtin_amdgcn_mfma_f32_16x16x32_bf16(af, b3, acc3, 0, 0, 0);
            bp += 256;
        }
    }

    // D[m=4g+j][n]: lane (r,g) reg j -> row row0+4g+j, col nt*16+r
    float* op = out + (size_t)row0 * DOUT;
#pragma unroll
    for (int j = 0; j < 4; ++j) {
        float* rp = op + (size_t)(4 * g + j) * DOUT + r;
        atomicAdd(rp,      acc0[j]);
        atomicAdd(rp + 16, acc1[j]);
        atomicAdd(rp + 32, acc2[j]);
        atomicAdd(rp + 48, acc3[j]);
    }
}

// ---------------------------------------------------------------------------
extern "C" void kernel_launch(void* const* d_in, const int* in_sizes, int n_in,
                              void* d_out, int out_size, void* d_ws, size_t ws_size,
                              hipStream_t stream) {
    const float* x   = (const float*)d_in[0];   // [8192, 256]
    const float* adj = (const float*)d_in[1];   // [3, 8192, 8192]
    const float* att = (const float*)d_in[2];   // [3]
    const float* w   = (const float*)d_in[3];   // [256, 64]
    const float* b   = (const float*)d_in[4];   // [64]
    float* out = (float*)d_out;                 // [8192, 64] fp32
    unsigned short* Bp = (unsigned short*)d_ws; // 3 MB packed bf16 B operand

    zero_out<<<NNODES * DOUT / 1024, 256, 0, stream>>>(out);
    prep_support<<<NNODES / 4, 256, 0, stream>>>(x, w, b, att, Bp);
    graphconv_gemm<<<NSTRIP * 4, 256, 0, stream>>>(adj, Bp, out);
}

// Round 12
// 194.361 us; speedup vs baseline: 1.3589x; 1.3589x over previous
//
#include <hip/hip_runtime.h>
#include <hip/hip_bf16.h>

// GraphConv: out = sum_a att[a] * (adj_a @ (X@W + b))
// N=8192, A=3, D_IN=256, D_OUT=64. fp32 in/out.
// Stacked-K GEMM  C[8192,64] = [adj0|adj1|adj2] @ [att0*S; att1*S; att2*S],
// S = X@W+b in bf16, packed MFMA-B-fragment order (d_ws).
// R12 = R10 + counted-vmcnt double buffer (the clean pipeline test):
//  - BK=256 (1KB/row granule, at the measured saturation point).
//  - per-wave dbuf: 2 x 16KB halves, 128KB LDS, 1 block/CU, 1 wave/SIMD
//    -> VGPRs free; B-frags (32 x 16B) prefetched to regs each chunk.
//  - per iter: [32 B-loads (oldest)] [16 gload_lds chunk i+1]
//    [s_waitcnt vmcnt(16)] -> compute is pure LDS/VALU/MFMA while chunk
//    i+1's 16KB stays in flight. Dead-window (the 25% plateau term) gone.

#define NNODES 8192
#define DIN    256
#define DOUT   64
#define NA     3
#define KSTACK (NA * NNODES)     // 24576
#define KQ     (KSTACK / 4)      // 6144 per quarter
#define BK     256
#define NCH    (KQ / BK)         // 24 chunks per wave
#define NSTRIP (NNODES / 64)     // 128

typedef float f32x4 __attribute__((ext_vector_type(4)));
typedef short s16x8 __attribute__((ext_vector_type(8)));

__device__ __forceinline__ unsigned short f2bf(float f) {
    __hip_bfloat16 h = __float2bfloat16(f);
    return __builtin_bit_cast(unsigned short, h);
}

__device__ __forceinline__ s16x8 pack8(f32x4 a, f32x4 b) {
    s16x8 o;
    o[0] = (short)f2bf(a[0]); o[1] = (short)f2bf(a[1]);
    o[2] = (short)f2bf(a[2]); o[3] = (short)f2bf(a[3]);
    o[4] = (short)f2bf(b[0]); o[5] = (short)f2bf(b[1]);
    o[6] = (short)f2bf(b[2]); o[7] = (short)f2bf(b[3]);
    return o;
}

__device__ __forceinline__ void gload_lds16(const float* g, float* l) {
    // width 16B, offset 0, aux=2 (NT: adj is single-use, keep B in L2)
    __builtin_amdgcn_global_load_lds(
        (const __attribute__((address_space(1))) void*)g,
        (__attribute__((address_space(3))) void*)l, 16, 0, 2);
}

// ---------------------------------------------------------------------------
// Kernel 0: zero d_out (gemm accumulates into it atomically).
// ---------------------------------------------------------------------------
__global__ __launch_bounds__(256) void zero_out(float* __restrict__ out) {
    f32x4 z = {0.f, 0.f, 0.f, 0.f};
    ((f32x4*)out)[(blockIdx.x << 8) + threadIdx.x] = z;
}

// ---------------------------------------------------------------------------
// Kernel 1: S = X@W + b; write att[a]*S in packed bf16 B-fragment layout:
// tile (kt_abs, nt): B[k_local][col], k_local = (lane>>4)*8 + j, col = lane&15;
// flat shorts = (kt_abs*4 + nt)*512 + lane*8 + j.
// ---------------------------------------------------------------------------
__global__ __launch_bounds__(256) void prep_support(
    const float* __restrict__ x, const float* __restrict__ w,
    const float* __restrict__ bias, const float* __restrict__ att,
    unsigned short* __restrict__ Bp)
{
    const int t = threadIdx.x;
    const int d = t & 63;
    const int m = (blockIdx.x << 2) + (t >> 6);

    const float* xr = x + (size_t)m * DIN;
    float acc = bias[d];
#pragma unroll 4
    for (int k = 0; k < DIN; k += 4) {
        f32x4 xv = *(const f32x4*)(xr + k);
        acc += xv[0] * w[(k + 0) * DOUT + d];
        acc += xv[1] * w[(k + 1) * DOUT + d];
        acc += xv[2] * w[(k + 2) * DOUT + d];
        acc += xv[3] * w[(k + 3) * DOUT + d];
    }

    const int kt   = m >> 5;
    const int kl   = m & 31;
    const int lane = ((kl >> 3) << 4) | (d & 15);
    const int j    = kl & 7;
    const int nt   = d >> 4;

    const size_t base    = (size_t)(kt * 4 + nt) * 512 + lane * 8 + j;
    const size_t aStride = (size_t)(NNODES / 32) * 4 * 512;

    const float a0 = att[0], a1 = att[1], a2 = att[2];
    Bp[base]               = f2bf(a0 * acc);
    Bp[base + aStride]     = f2bf(a1 * acc);
    Bp[base + 2 * aStride] = f2bf(a2 * acc);
}

// ---------------------------------------------------------------------------
// stage one chunk (16 rows x 1KB) into a wave-private buffer half.
// 1 instr = 1 row; linear LDS dest (HW adds lane*16B), XOR-preswizzled src.
// ---------------------------------------------------------------------------
__device__ __forceinline__ void stage_chunk(
    const float* __restrict__ adj, int row0, int k0, float* bufbase, int lane)
{
    const float* ab = adj + ((size_t)(k0 >> 13) << 26) + (k0 & 8191);
#pragma unroll
    for (int p = 0; p < 16; ++p) {
        const float* gp = ab + (size_t)(row0 + p) * NNODES
                             + ((lane ^ (p & 7)) << 2);
        gload_lds16(gp, bufbase + (p << 8));
    }
}

// ---------------------------------------------------------------------------
// Kernel 2: bid = strip*4 + q. Wave wv owns rows [strip*64 + wv*16, +16) and
// k in [q*6144, +6144), 24 chunks of 256 (staggered start), double-buffered:
//   iter i: [32 B-frag loads -> regs (oldest in VMEM FIFO)]
//           [stage chunk i+1 -> other half (16 gload_lds)]
//           [s_waitcnt vmcnt(16): chunk i + B done, i+1 in flight]
//           [compute: 8 k-tiles x {2 swizzled ds_read_b128, pack, 4 MFMA}]
// No barriers, wave-private. Atomic fp32 epilogue (4 contributions/elem).
// ---------------------------------------------------------------------------
__global__ __launch_bounds__(256, 1) void graphconv_gemm(
    const float* __restrict__ adj, const unsigned short* __restrict__ Bp,
    float* __restrict__ out)
{
    __shared__ float ldsf[32768];            // 128 KB: wave wv -> [wv*8192, +8192)

    const int tid  = threadIdx.x;
    const int wv   = tid >> 6;
    const int lane = tid & 63;
    const int r    = lane & 15;              // A row within tile / C col
    const int g    = lane >> 4;              // k-subgroup
    const int r7   = r & 7;
    const int q     = blockIdx.x & 3;        // K-quarter
    const int strip = blockIdx.x >> 2;
    const int row0  = strip * 64 + wv * 16;

    float* wbase = &ldsf[wv << 13];          // 2 x 4096-float halves

    f32x4 acc0 = {0.f, 0.f, 0.f, 0.f};
    f32x4 acc1 = {0.f, 0.f, 0.f, 0.f};
    f32x4 acc2 = {0.f, 0.f, 0.f, 0.f};
    f32x4 acc3 = {0.f, 0.f, 0.f, 0.f};

    const int c0 = (wv * 6 + strip) % NCH;   // desync k-walk phases

    // prologue: stage chunk c0 into half 0
    stage_chunk(adj, row0, q * KQ + c0 * BK, wbase, lane);

    for (int i = 0; i < NCH; ++i) {
        int c = c0 + i; if (c >= NCH) c -= NCH;
        const int k0  = q * KQ + c * BK;
        const int cur = i & 1;

        // 1. B fragments for chunk i -> regs (issued before next staging,
        //    so vmcnt(16) covers them). 32 x 16B from the XCD-pinned slice.
        const s16x8* __restrict__ bp =
            (const s16x8*)Bp + ((size_t)(k0 >> 5) << 8) + lane;
        s16x8 bq[32];
#pragma unroll
        for (int t = 0; t < 8; ++t)
#pragma unroll
            for (int n = 0; n < 4; ++n)
                bq[t * 4 + n] = bp[t * 256 + n * 64];

        __builtin_amdgcn_sched_barrier(0);

        // 2. stage chunk i+1 into the other half
        const bool more = (i + 1 < NCH);
        if (more) {
            int cn = c + 1; if (cn >= NCH) cn = 0;
            stage_chunk(adj, row0, q * KQ + cn * BK, wbase + ((cur ^ 1) << 12), lane);
            // 3. chunk i staging + B arrived; chunk i+1's 16 stay in flight
            asm volatile("s_waitcnt vmcnt(16)" ::: "memory");
        } else {
            asm volatile("s_waitcnt vmcnt(0)" ::: "memory");
        }
        __builtin_amdgcn_sched_barrier(0);

        // 4. pure-LDS compute: 8 k-tiles
        const float* lrow = wbase + (cur << 12) + (r << 8);  // row r base
#pragma unroll
        for (int t = 0; t < 8; ++t) {
            const int s0 = ((t << 3) + 2 * g)     ^ r7;      // 16B slots
            const int s1 = ((t << 3) + 2 * g + 1) ^ r7;
            f32x4 v0 = *(const f32x4*)(lrow + (s0 << 2));
            f32x4 v1 = *(const f32x4*)(lrow + (s1 << 2));
            s16x8 af = pack8(v0, v1);
            acc0 = __builtin_amdgcn_mfma_f32_16x16x32_bf16(af, bq[t*4+0], acc0, 0, 0, 0);
            acc1 = __builtin_amdgcn_mfma_f32_16x16x32_bf16(af, bq[t*4+1], acc1, 0, 0, 0);
            acc2 = __builtin_amdgcn_mfma_f32_16x16x32_bf16(af, bq[t*4+2], acc2, 0, 0, 0);
            acc3 = __builtin_amdgcn_mfma_f32_16x16x32_bf16(af, bq[t*4+3], acc3, 0, 0, 0);
        }
    }

    // D[m=4g+j][n]: lane (r,g) reg j -> row row0+4g+j, col nt*16+r
    float* op = out + (size_t)row0 * DOUT;
#pragma unroll
    for (int j = 0; j < 4; ++j) {
        float* rp = op + (size_t)(4 * g + j) * DOUT + r;
        atomicAdd(rp,      acc0[j]);
        atomicAdd(rp + 16, acc1[j]);
        atomicAdd(rp + 32, acc2[j]);
        atomicAdd(rp + 48, acc3[j]);
    }
}

// ---------------------------------------------------------------------------
extern "C" void kernel_launch(void* const* d_in, const int* in_sizes, int n_in,
                              void* d_out, int out_size, void* d_ws, size_t ws_size,
                              hipStream_t stream) {
    const float* x   = (const float*)d_in[0];   // [8192, 256]
    const float* adj = (const float*)d_in[1];   // [3, 8192, 8192]
    const float* att = (const float*)d_in[2];   // [3]
    const float* w   = (const float*)d_in[3];   // [256, 64]
    const float* b   = (const float*)d_in[4];   // [64]
    float* out = (float*)d_out;                 // [8192, 64] fp32
    unsigned short* Bp = (unsigned short*)d_ws; // 3 MB packed bf16 B operand

    zero_out<<<NNODES * DOUT / 1024, 256, 0, stream>>>(out);
    prep_support<<<NNODES / 4, 256, 0, stream>>>(x, w, b, att, Bp);
    graphconv_gemm<<<NSTRIP * 4, 256, 0, stream>>>(adj, Bp, out);
}

// Round 13
// 184.836 us; speedup vs baseline: 1.4289x; 1.0515x over previous
//
#include <hip/hip_runtime.h>
#include <hip/hip_bf16.h>

// GraphConv: out = sum_a att[a] * (adj_a @ (X@W + b))
// N=8192, A=3, D_IN=256, D_OUT=64. fp32 in/out.
// Stacked-K GEMM  C[8192,64] = [adj0|adj1|adj2] @ [att0*S; att1*S; att2*S],
// S = X@W+b in bf16, packed MFMA-B-fragment order (d_ws).
// R13 = R10 verbatim (best measured: 185.1 us, ~75% of copy-ubench HBM
// ceiling). 13-round falsification matrix: granule saturated at 1KB,
// occupancy/bytes/pipelining/k-order all flat-or-negative. The 16-row
// strided stream pattern (forced by MFMA tiling + LDS capacity) at 1-2KB
// granule is the structural limit; this is the practical roofline.

#define NNODES 8192
#define DIN    256
#define DOUT   64
#define NA     3
#define KSTACK (NA * NNODES)     // 24576
#define KQ     (KSTACK / 4)      // 6144 per quarter
#define BK     512
#define NCH    (KQ / BK)         // 12 chunks per wave
#define NSTRIP (NNODES / 64)     // 128

typedef float f32x4 __attribute__((ext_vector_type(4)));
typedef short s16x8 __attribute__((ext_vector_type(8)));

__device__ __forceinline__ unsigned short f2bf(float f) {
    __hip_bfloat16 h = __float2bfloat16(f);
    return __builtin_bit_cast(unsigned short, h);
}

__device__ __forceinline__ s16x8 pack8(f32x4 a, f32x4 b) {
    s16x8 o;
    o[0] = (short)f2bf(a[0]); o[1] = (short)f2bf(a[1]);
    o[2] = (short)f2bf(a[2]); o[3] = (short)f2bf(a[3]);
    o[4] = (short)f2bf(b[0]); o[5] = (short)f2bf(b[1]);
    o[6] = (short)f2bf(b[2]); o[7] = (short)f2bf(b[3]);
    return o;
}

__device__ __forceinline__ void gload_lds16(const float* g, float* l) {
    // width 16B, offset 0, aux=2 (NT: adj is single-use, keep B in L2)
    __builtin_amdgcn_global_load_lds(
        (const __attribute__((address_space(1))) void*)g,
        (__attribute__((address_space(3))) void*)l, 16, 0, 2);
}

// ---------------------------------------------------------------------------
// Kernel 0: zero d_out (gemm accumulates into it atomically).
// ---------------------------------------------------------------------------
__global__ __launch_bounds__(256) void zero_out(float* __restrict__ out) {
    f32x4 z = {0.f, 0.f, 0.f, 0.f};
    ((f32x4*)out)[(blockIdx.x << 8) + threadIdx.x] = z;
}

// ---------------------------------------------------------------------------
// Kernel 1: S = X@W + b; write att[a]*S in packed bf16 B-fragment layout:
// tile (kt_abs, nt): B[k_local][col], k_local = (lane>>4)*8 + j, col = lane&15;
// flat shorts = (kt_abs*4 + nt)*512 + lane*8 + j.
// ---------------------------------------------------------------------------
__global__ __launch_bounds__(256) void prep_support(
    const float* __restrict__ x, const float* __restrict__ w,
    const float* __restrict__ bias, const float* __restrict__ att,
    unsigned short* __restrict__ Bp)
{
    const int t = threadIdx.x;
    const int d = t & 63;
    const int m = (blockIdx.x << 2) + (t >> 6);

    const float* xr = x + (size_t)m * DIN;
    float acc = bias[d];
#pragma unroll 4
    for (int k = 0; k < DIN; k += 4) {
        f32x4 xv = *(const f32x4*)(xr + k);
        acc += xv[0] * w[(k + 0) * DOUT + d];
        acc += xv[1] * w[(k + 1) * DOUT + d];
        acc += xv[2] * w[(k + 2) * DOUT + d];
        acc += xv[3] * w[(k + 3) * DOUT + d];
    }

    const int kt   = m >> 5;
    const int kl   = m & 31;
    const int lane = ((kl >> 3) << 4) | (d & 15);
    const int j    = kl & 7;
    const int nt   = d >> 4;

    const size_t base    = (size_t)(kt * 4 + nt) * 512 + lane * 8 + j;
    const size_t aStride = (size_t)(NNODES / 32) * 4 * 512;

    const float a0 = att[0], a1 = att[1], a2 = att[2];
    Bp[base]               = f2bf(a0 * acc);
    Bp[base + aStride]     = f2bf(a1 * acc);
    Bp[base + 2 * aStride] = f2bf(a2 * acc);
}

// ---------------------------------------------------------------------------
// Kernel 2: bid = strip*4 + q. Wave wv owns rows [strip*64 + wv*16, +16) and
// k in [q*6144, +6144), walked as 12 chunks of 512 (staggered start).
// Per chunk: 32x global_load_lds (1 instr = 1KB half-row; 2 per row -> 2KB
// contiguous per row per chunk), vmcnt(0), then 16 k-tiles of {2 swizzled
// ds_read_b128, pack, 4 B-frag loads (L2), 4 mfma_16x16x32_bf16}.
// No barriers, wave-private 32KB fp32 buffers. Atomic epilogue.
// ---------------------------------------------------------------------------
__global__ __launch_bounds__(256, 1) void graphconv_gemm(
    const float* __restrict__ adj, const unsigned short* __restrict__ Bp,
    float* __restrict__ out)
{
    __shared__ float ldsf[32768];            // 128 KB: wave wv -> [wv*8192, +8192)

    const int tid  = threadIdx.x;
    const int wv   = tid >> 6;
    const int lane = tid & 63;
    const int r    = lane & 15;              // A row within tile / C col
    const int g    = lane >> 4;              // k-subgroup
    const int r7   = r & 7;
    const int q     = blockIdx.x & 3;        // K-quarter
    const int strip = blockIdx.x >> 2;
    const int row0  = strip * 64 + wv * 16;

    float* wbuf = &ldsf[wv << 13];           // 32 KB wave-private buffer

    f32x4 acc0 = {0.f, 0.f, 0.f, 0.f};
    f32x4 acc1 = {0.f, 0.f, 0.f, 0.f};
    f32x4 acc2 = {0.f, 0.f, 0.f, 0.f};
    f32x4 acc3 = {0.f, 0.f, 0.f, 0.f};

    const int c0 = (wv * 3 + strip) % NCH;   // desync k-walk phases

    for (int i = 0; i < NCH; ++i) {
        int c = c0 + i; if (c >= NCH) c -= NCH;
        const int k0 = q * KQ + c * BK;                        // stacked k
        const float* ab = adj + ((size_t)(k0 >> 13) << 26) + (k0 & 8191);

        // stage 16 rows x 2KB (2 halves of 1KB), linear LDS dest +
        // XOR-preswizzled source (swizzle within each 64-slot half)
#pragma unroll
        for (int p = 0; p < 16; ++p) {
            const float* rpg = ab + (size_t)(row0 + p) * NNODES;
            const int sl = ((lane ^ (p & 7)) << 2);
            float* ld = wbuf + (p << 9) + (lane << 2);
            gload_lds16(rpg + sl,       ld);
            gload_lds16(rpg + 256 + sl, ld + 256);
        }
        asm volatile("s_waitcnt vmcnt(0)" ::: "memory");
        __builtin_amdgcn_sched_barrier(0);

        const s16x8* bp = (const s16x8*)Bp + ((size_t)(k0 >> 5) << 8) + lane;
        const float* lrow = wbuf + (r << 9); // row r base (512 floats/row)
#pragma unroll
        for (int t = 0; t < 16; ++t) {
            // logical 16B slots a0 = t*8+2g, a1 = a0+1 (0..127);
            // physical = (a & 64) | ((a & 63) ^ r7)
            const int a0 = (t << 3) + 2 * g;
            const int a1 = a0 + 1;
            const int p0 = (a0 & 64) | ((a0 & 63) ^ r7);
            const int p1 = (a1 & 64) | ((a1 & 63) ^ r7);
            f32x4 v0 = *(const f32x4*)(lrow + (p0 << 2));
            f32x4 v1 = *(const f32x4*)(lrow + (p1 << 2));
            s16x8 af = pack8(v0, v1);
            s16x8 b0 = bp[0];
            s16x8 b1 = bp[64];
            s16x8 b2 = bp[128];
            s16x8 b3 = bp[192];
            acc0 = __builtin_amdgcn_mfma_f32_16x16x32_bf16(af, b0, acc0, 0, 0, 0);
            acc1 = __builtin_amdgcn_mfma_f32_16x16x32_bf16(af, b1, acc1, 0, 0, 0);
            acc2 = __builtin_amdgcn_mfma_f32_16x16x32_bf16(af, b2, acc2, 0, 0, 0);
            acc3 = __builtin_amdgcn_mfma_f32_16x16x32_bf16(af, b3, acc3, 0, 0, 0);
            bp += 256;
        }
    }

    // D[m=4g+j][n]: lane (r,g) reg j -> row row0+4g+j, col nt*16+r
    float* op = out + (size_t)row0 * DOUT;
#pragma unroll
    for (int j = 0; j < 4; ++j) {
        float* rp = op + (size_t)(4 * g + j) * DOUT + r;
        atomicAdd(rp,      acc0[j]);
        atomicAdd(rp + 16, acc1[j]);
        atomicAdd(rp + 32, acc2[j]);
        atomicAdd(rp + 48, acc3[j]);
    }
}

// ---------------------------------------------------------------------------
extern "C" void kernel_launch(void* const* d_in, const int* in_sizes, int n_in,
                              void* d_out, int out_size, void* d_ws, size_t ws_size,
                              hipStream_t stream) {
    const float* x   = (const float*)d_in[0];   // [8192, 256]
    const float* adj = (const float*)d_in[1];   // [3, 8192, 8192]
    const float* att = (const float*)d_in[2];   // [3]
    const float* w   = (const float*)d_in[3];   // [256, 64]
    const float* b   = (const float*)d_in[4];   // [64]
    float* out = (float*)d_out;                 // [8192, 64] fp32
    unsigned short* Bp = (unsigned short*)d_ws; // 3 MB packed bf16 B operand

    zero_out<<<NNODES * DOUT / 1024, 256, 0, stream>>>(out);
    prep_support<<<NNODES / 4, 256, 0, stream>>>(x, w, b, att, Bp);
    graphconv_gemm<<<NSTRIP * 4, 256, 0, stream>>>(adj, Bp, out);
}